// Round 1
// baseline (238.676 us; speedup 1.0000x reference)
//
#include <hip/hip_runtime.h>
#include <hip/hip_bf16.h>
#include <math.h>

// ---------------------------------------------------------------------------
// Problem shapes
// ---------------------------------------------------------------------------
#define NN 400000
#define HH 256
#define GG 1024
#define E1 7
#define E2 70
#define E3 300

// Output layout (flat f32):
//   ec1_logits [1024*7]    @ 0
//   ec2_logits [1024*70]   @ 7168
//   ec3_logits [1024*300]  @ 78848
//   ec1_probs  [1024*7]    @ 386048
//   g          [1024*256]  @ 393216
#define OFF_L1 0
#define OFF_L2 7168
#define OFF_L3 78848
#define OFF_P1 386048
#define OFF_G  393216

// ---------------------------------------------------------------------------
// Kernel 1: segment mean.  One block (256 thr = 4 waves) per graph.
// batch_idx is sorted ascending -> binary search the segment bounds.
// Each wave reads whole 1KB rows via float4 (64 lanes x 16B).
// ---------------------------------------------------------------------------
__global__ __launch_bounds__(256) void seg_mean_kernel(
    const float* __restrict__ emb, const int* __restrict__ bidx,
    float* __restrict__ gf) {
  const int g = blockIdx.x;
  const int tid = threadIdx.x;
  __shared__ int seg[2];
  if (tid < 2) {
    const int target = g + tid;  // lower_bound(target)
    int lo = 0, hi = NN;
    while (lo < hi) {
      int mid = (lo + hi) >> 1;
      if (bidx[mid] < target) lo = mid + 1; else hi = mid;
    }
    seg[tid] = lo;
  }
  __syncthreads();
  const int start = seg[0], end = seg[1];
  const int cnt = end - start;

  const int wave = tid >> 6, lane = tid & 63;
  const float4* __restrict__ embv = (const float4*)emb;  // row stride 64

  float a0x = 0.f, a0y = 0.f, a0z = 0.f, a0w = 0.f;
  float a1x = 0.f, a1y = 0.f, a1z = 0.f, a1w = 0.f;
  float a2x = 0.f, a2y = 0.f, a2z = 0.f, a2w = 0.f;
  float a3x = 0.f, a3y = 0.f, a3z = 0.f, a3w = 0.f;

  int r = start + wave;
  for (; r + 12 < end; r += 16) {
    float4 v0 = embv[(size_t)r * 64 + lane];
    float4 v1 = embv[(size_t)(r + 4) * 64 + lane];
    float4 v2 = embv[(size_t)(r + 8) * 64 + lane];
    float4 v3 = embv[(size_t)(r + 12) * 64 + lane];
    a0x += v0.x; a0y += v0.y; a0z += v0.z; a0w += v0.w;
    a1x += v1.x; a1y += v1.y; a1z += v1.z; a1w += v1.w;
    a2x += v2.x; a2y += v2.y; a2z += v2.z; a2w += v2.w;
    a3x += v3.x; a3y += v3.y; a3z += v3.z; a3w += v3.w;
  }
  for (; r < end; r += 4) {
    float4 v = embv[(size_t)r * 64 + lane];
    a0x += v.x; a0y += v.y; a0z += v.z; a0w += v.w;
  }
  a0x += a1x + a2x + a3x;
  a0y += a1y + a2y + a3y;
  a0z += a1z + a2z + a3z;
  a0w += a1w + a2w + a3w;

  __shared__ float4 part[4][64];
  part[wave][lane] = make_float4(a0x, a0y, a0z, a0w);
  __syncthreads();
  if (tid < 64) {
    float4 p0 = part[0][tid], p1 = part[1][tid], p2 = part[2][tid], p3 = part[3][tid];
    const float inv = 1.0f / (float)max(cnt, 1);
    float4 s;
    s.x = (p0.x + p1.x + p2.x + p3.x) * inv;
    s.y = (p0.y + p1.y + p2.y + p3.y) * inv;
    s.z = (p0.z + p1.z + p2.z + p3.z) * inv;
    s.w = (p0.w + p1.w + p2.w + p3.w) * inv;
    ((float4*)gf)[g * 64 + tid] = s;
  }
}

// ---------------------------------------------------------------------------
// Kernel 2: fused MLP cascade. 128 blocks x 8 graph-rows, 256 threads.
// All intermediates in LDS; weights stream from L2.
// ---------------------------------------------------------------------------
__device__ __forceinline__ float gelu_exact(float v) {
  return 0.5f * v * (1.0f + erff(v * 0.70710678118654752f));
}

// O[r][j] = (act? gelu : id)(b[j] + sum_k X[r][k] * W[k*M+j]) for r<R, j<M
__device__ __forceinline__ void dense(const float* __restrict__ X, int ldx,
                                      const float* __restrict__ W,
                                      const float* __restrict__ b,
                                      int R, int K, int M,
                                      float* __restrict__ O, int ldo, bool act) {
  const int tid = threadIdx.x;
  for (int idx = tid; idx < R * M; idx += 256) {
    const int r = idx / M;
    const int j = idx - r * M;
    const float* xr = X + r * ldx;
    float acc = b[j];
    int k = 0;
    for (; k + 3 < K; k += 4) {
      acc += xr[k]     * W[(k)     * M + j];
      acc += xr[k + 1] * W[(k + 1) * M + j];
      acc += xr[k + 2] * W[(k + 2) * M + j];
      acc += xr[k + 3] * W[(k + 3) * M + j];
    }
    for (; k < K; ++k) acc += xr[k] * W[k * M + j];
    O[r * ldo + j] = act ? gelu_exact(acc) : acc;
  }
}

// in-place row softmax on O[R][M] (ld = ldo), one thread per row
__device__ __forceinline__ void softmax_rows(float* O, int ldo, int R, int M) {
  const int tid = threadIdx.x;
  if (tid < R) {
    float* row = O + tid * ldo;
    float m = row[0];
    for (int j = 1; j < M; ++j) m = fmaxf(m, row[j]);
    float s = 0.f;
    for (int j = 0; j < M; ++j) { float e = expf(row[j] - m); row[j] = e; s += e; }
    const float inv = 1.0f / s;
    for (int j = 0; j < M; ++j) row[j] *= inv;
  }
}

__global__ __launch_bounds__(256) void mlp_kernel(
    const float* __restrict__ gf,
    const float* __restrict__ pool_w, const float* __restrict__ pool_b,
    const float* __restrict__ w11, const float* __restrict__ b11,
    const float* __restrict__ w12, const float* __restrict__ b12,
    const float* __restrict__ w21, const float* __restrict__ b21,
    const float* __restrict__ w22, const float* __restrict__ b22,
    const float* __restrict__ w31, const float* __restrict__ b31,
    const float* __restrict__ w32, const float* __restrict__ b32,
    float* __restrict__ out) {
  const int R = 8;
  const int rs = blockIdx.x * R;
  const int tid = threadIdx.x;

  __shared__ float x[8][344];  // concat input buffer, K up to 333
  __shared__ float h[8][136];  // hidden (128)
  __shared__ float o[8][304];  // stage output, M up to 300

  // load pooled features
  for (int idx = tid; idx < R * 256; idx += 256) {
    const int r = idx >> 8, j = idx & 255;
    x[r][j] = gf[(rs + r) * 256 + j];
  }
  __syncthreads();

  // g = gelu(gf @ pool_w + pool_b)  [8][256] -> o
  dense(&x[0][0], 344, pool_w, pool_b, R, 256, 256, &o[0][0], 304, true);
  __syncthreads();
  // o -> x[:, :256], write g to out
  for (int idx = tid; idx < R * 256; idx += 256) {
    const int r = idx >> 8, j = idx & 255;
    const float v = o[r][j];
    x[r][j] = v;
    out[OFF_G + (rs + r) * 256 + j] = v;
  }
  __syncthreads();

  // ec1: hidden = gelu(x[:, :256] @ w11 + b11)  [8][128]
  dense(&x[0][0], 344, w11, b11, R, 256, 128, &h[0][0], 136, true);
  __syncthreads();
  // logits1 = hidden @ w12 + b12  [8][7]
  dense(&h[0][0], 136, w12, b12, R, 128, E1, &o[0][0], 304, false);
  __syncthreads();
  for (int idx = tid; idx < R * E1; idx += 256) {
    const int r = idx / E1, j = idx - r * E1;
    out[OFF_L1 + (rs + r) * E1 + j] = o[r][j];
  }
  __syncthreads();
  softmax_rows(&o[0][0], 304, R, E1);
  __syncthreads();
  for (int idx = tid; idx < R * E1; idx += 256) {
    const int r = idx / E1, j = idx - r * E1;
    const float v = o[r][j];
    out[OFF_P1 + (rs + r) * E1 + j] = v;
    x[r][256 + j] = v;
  }
  __syncthreads();

  // ec2: hidden = gelu(x[:, :263] @ w21 + b21)
  dense(&x[0][0], 344, w21, b21, R, 256 + E1, 128, &h[0][0], 136, true);
  __syncthreads();
  dense(&h[0][0], 136, w22, b22, R, 128, E2, &o[0][0], 304, false);
  __syncthreads();
  for (int idx = tid; idx < R * E2; idx += 256) {
    const int r = idx / E2, j = idx - r * E2;
    out[OFF_L2 + (rs + r) * E2 + j] = o[r][j];
  }
  __syncthreads();
  softmax_rows(&o[0][0], 304, R, E2);
  __syncthreads();
  for (int idx = tid; idx < R * E2; idx += 256) {
    const int r = idx / E2, j = idx - r * E2;
    x[r][256 + E1 + j] = o[r][j];
  }
  __syncthreads();

  // ec3: hidden = gelu(x[:, :333] @ w31 + b31)
  dense(&x[0][0], 344, w31, b31, R, 256 + E1 + E2, 128, &h[0][0], 136, true);
  __syncthreads();
  dense(&h[0][0], 136, w32, b32, R, 128, E3, &o[0][0], 304, false);
  __syncthreads();
  for (int idx = tid; idx < R * E3; idx += 256) {
    const int r = idx / E3, j = idx - r * E3;
    out[OFF_L3 + (rs + r) * E3 + j] = o[r][j];
  }
}

// ---------------------------------------------------------------------------
extern "C" void kernel_launch(void* const* d_in, const int* in_sizes, int n_in,
                              void* d_out, int out_size, void* d_ws, size_t ws_size,
                              hipStream_t stream) {
  const float* emb    = (const float*)d_in[0];
  const int*   bidx   = (const int*)d_in[1];
  const float* pool_w = (const float*)d_in[2];
  const float* pool_b = (const float*)d_in[3];
  const float* w11    = (const float*)d_in[4];
  const float* b11    = (const float*)d_in[5];
  const float* w12    = (const float*)d_in[6];
  const float* b12    = (const float*)d_in[7];
  const float* w21    = (const float*)d_in[8];
  const float* b21    = (const float*)d_in[9];
  const float* w22    = (const float*)d_in[10];
  const float* b22    = (const float*)d_in[11];
  const float* w31    = (const float*)d_in[12];
  const float* b31    = (const float*)d_in[13];
  const float* w32    = (const float*)d_in[14];
  const float* b32    = (const float*)d_in[15];
  float* out = (float*)d_out;
  float* gf = (float*)d_ws;  // [1024][256] f32 = 1 MB

  seg_mean_kernel<<<GG, 256, 0, stream>>>(emb, bidx, gf);
  mlp_kernel<<<GG / 8, 256, 0, stream>>>(gf, pool_w, pool_b,
                                         w11, b11, w12, b12,
                                         w21, b21, w22, b22,
                                         w31, b31, w32, b32, out);
}